// Round 1
// baseline (668.847 us; speedup 1.0000x reference)
//
#include <hip/hip_runtime.h>

// Problem constants (match reference)
#define TT 20      // timesteps
#define GG 1024    // groups
#define PP 64      // pedestrians per group
#define BB (GG*PP) // 65536
#define THR 0.25f

// Each block handles half of one group (32 of the 64 "i" rows).
// grid = 2*GG blocks, 256 threads.
//   lane j = tid & 63 is fixed for the whole block -> x_j[t] preloaded to regs
//   i = half*32 + chunk*4 + (tid>>6), chunk = 0..7
// Output layout: out[g*PP*PP*TT + (i*PP + j)*TT + t]  (t contiguous)
__global__ __launch_bounds__(256) void traj_critic_kernel(
    const float* __restrict__ traj, float* __restrict__ out)
{
    __shared__ float xs[TT * PP * 2];   // 10 KB: xs[t*128 + p*2 + c]

    const int blk  = blockIdx.x;
    const int g    = blk >> 1;
    const int half = blk & 1;
    const int tid  = threadIdx.x;

    // ---- cooperative group load: 2560 floats = 640 float4 ----
    // float4 index u4: t = u4>>5 (32 float4 per t), rem4 = u4&31
    // global float4 idx = t*(BB*2/4) + g*32 + rem4 = t*32768 + g*32 + rem4
    {
        const float4* tg = (const float4*)traj;
        float4* ls = (float4*)xs;
        for (int u4 = tid; u4 < (TT * PP * 2 / 4); u4 += 256) {
            int t    = u4 >> 5;
            int rem4 = u4 & 31;
            ls[u4] = tg[t * 32768 + g * 32 + rem4];
        }
    }
    __syncthreads();

    const int j   = tid & 63;
    const int wid = tid >> 6;

    // preload x_j for all t (40 VGPRs). stride-2-float access: 2-way bank
    // aliasing = free on CDNA4.
    float2 xj[TT];
    const float2* xs2 = (const float2*)xs;
#pragma unroll
    for (int t = 0; t < TT; ++t) {
        xj[t] = xs2[t * PP + j];
    }

    float* outg = out + (size_t)g * (PP * PP * TT);

#pragma unroll 1
    for (int c = 0; c < 8; ++c) {
        const int i = half * 32 + c * 4 + wid;
        const bool diag = (i == j);

        float cst[TT];
#pragma unroll
        for (int t = 0; t < TT; ++t) {
            // wave-uniform address -> LDS broadcast read (conflict-free)
            float2 xi = xs2[t * PP + i];
            float dx = xi.x - xj[t].x;
            float dy = xi.y - xj[t].y;
            float d2 = dx * dx + dy * dy;
            float d  = sqrtf(d2);
            float v  = THR - d;
            v = v > 0.0f ? v : 0.0f;
            cst[t] = diag ? 0.0f : v;
        }

        // 20 contiguous floats per thread -> 5 float4 stores (80B aligned)
        float4* op = (float4*)(outg + (size_t)(i * PP + j) * TT);
#pragma unroll
        for (int v4 = 0; v4 < 5; ++v4) {
            op[v4] = make_float4(cst[v4 * 4 + 0], cst[v4 * 4 + 1],
                                 cst[v4 * 4 + 2], cst[v4 * 4 + 3]);
        }
    }
}

extern "C" void kernel_launch(void* const* d_in, const int* in_sizes, int n_in,
                              void* d_out, int out_size, void* d_ws, size_t ws_size,
                              hipStream_t stream) {
    const float* traj = (const float*)d_in[0];  // (T, B, 2) f32
    float* out = (float*)d_out;                 // G*P*P*T f32
    traj_critic_kernel<<<2 * GG, 256, 0, stream>>>(traj, out);
}

// Round 2
// 399.734 us; speedup vs baseline: 1.6732x; 1.6732x over previous
//
#include <hip/hip_runtime.h>

// Problem constants (match reference)
#define TT 20      // timesteps
#define GG 1024    // groups
#define PP 64      // pedestrians per group
#define THR 0.25f
#define LDSS 65    // padded t-row stride in float2 units (64 + 1)

// grid = 2*GG blocks, 256 threads. Block handles half a group's i-rows
// (32 rows) in 8 chunks of 4 rows. Output region per chunk = 5120 contiguous
// floats; thread writes float4 at f4 = k*256 + tid (k=0..4) -> every wave
// store is 1024 contiguous bytes (full coalescing). Each of the 4 floats
// derives (pair, t) = (f/20, f%20) and computes cost from LDS directly.
__global__ __launch_bounds__(256) void traj_critic_kernel(
    const float* __restrict__ traj, float* __restrict__ out)
{
    __shared__ float2 xs[TT * LDSS];   // 10400 B; xs[t*65 + p] = (x,y) of ped p at t

    const int blk  = blockIdx.x;
    const int g    = blk >> 1;
    const int half = blk & 1;
    const int tid  = threadIdx.x;

    // ---- cooperative group load: 640 float4 -> padded LDS ----
    {
        const float4* tg = (const float4*)traj;
        for (int u4 = tid; u4 < (TT * PP * 2 / 4); u4 += 256) {
            int t = u4 >> 5;        // 32 float4 per timestep row
            int r = u4 & 31;        // float4 within row (= pair 2r, 2r+1)
            float4 v = tg[t * 32768 + g * 32 + r];
            xs[t * LDSS + 2 * r]     = make_float2(v.x, v.y);
            xs[t * LDSS + 2 * r + 1] = make_float2(v.z, v.w);
        }
    }
    __syncthreads();

#pragma unroll 1
    for (int c = 0; c < 8; ++c) {
        const int i0 = half * 32 + c * 4;            // 4 consecutive i rows
        float* regp = out + ((size_t)g * 4096 + (size_t)i0 * 64) * TT;

#pragma unroll
        for (int k = 0; k < 5; ++k) {
            const int fbase = (k * 256 + tid) * 4;   // flat float offset in region
            float vals[4];
#pragma unroll
            for (int e = 0; e < 4; ++e) {
                unsigned f = (unsigned)(fbase + e);
                unsigned p = f / 20u;                // pair index in [0,256)
                unsigned t = f - 20u * p;            // timestep
                int i = i0 + (int)(p >> 6);
                int j = (int)(p & 63u);
                float2 xi = xs[t * LDSS + i];
                float2 xj = xs[t * LDSS + j];
                float dx = xi.x - xj.x;
                float dy = xi.y - xj.y;
                float d  = sqrtf(dx * dx + dy * dy);
                float v  = THR - d;
                v = v > 0.0f ? v : 0.0f;
                vals[e] = (i == j) ? 0.0f : v;
            }
            *(float4*)(regp + fbase) =
                make_float4(vals[0], vals[1], vals[2], vals[3]);
        }
        // LDS is read-only after staging: no barrier between chunks needed
    }
}

extern "C" void kernel_launch(void* const* d_in, const int* in_sizes, int n_in,
                              void* d_out, int out_size, void* d_ws, size_t ws_size,
                              hipStream_t stream) {
    const float* traj = (const float*)d_in[0];  // (T, B, 2) f32
    float* out = (float*)d_out;                 // G*P*P*T f32
    traj_critic_kernel<<<2 * GG, 256, 0, stream>>>(traj, out);
}

// Round 3
// 354.208 us; speedup vs baseline: 1.8883x; 1.1285x over previous
//
#include <hip/hip_runtime.h>

// Problem constants (match reference)
#define TT 20      // timesteps
#define GG 1024    // groups
#define PP 64      // pedestrians per group
#define THR 0.25f
#define XPAD 65    // padded t-row stride in float2 units (64 + 1)

// grid = 2*GG blocks, 256 threads; block handles half a group (32 i-rows)
// in 8 chunks of 4 rows.
//
// Compute phase (cheap, R0-style): thread = pair (i = i0 + tid>>6, j = tid&63).
//   xj[t] preloaded to 40 VGPRs once per block; xi[t] is a wave-uniform LDS
//   broadcast. ~8 VALU/elem, no div/mod, raw v_sqrt_f32.
//
// Store phase: in-LDS transpose with block-swizzle so BOTH sides are
// conflict-free b128:
//   logical float4-block of chunk region: m in [0,1280)
//   physical slot: pi(m) = (m & ~7) | ((5*m) & 7)   (involution, permutes
//   each aligned 8-group; writer blocks m = 5*tid+kt -> groups (tid+5kt)&7
//   spread; reader blocks m = k*256+tid -> groups (5*tid)&7 spread)
//   Reader stores lane-contiguous float4s -> 1KB per wave-store instr.
__global__ __launch_bounds__(256) void traj_critic_kernel(
    const float* __restrict__ traj, float* __restrict__ out)
{
    __shared__ float2 xs[TT * XPAD];   // 10400 B: xs[t*65 + p]
    __shared__ float4 buf[1280];       // 20480 B transpose buffer

    const int blk  = blockIdx.x;
    const int g    = blk >> 1;
    const int half = blk & 1;
    const int tid  = threadIdx.x;

    // ---- cooperative group load: 640 float4 -> padded LDS ----
    {
        const float4* tg = (const float4*)traj;
        for (int u4 = tid; u4 < (TT * PP * 2 / 4); u4 += 256) {
            int t = u4 >> 5;        // 32 float4 per timestep row
            int r = u4 & 31;
            float4 v = tg[t * 32768 + g * 32 + r];
            xs[t * XPAD + 2 * r]     = make_float2(v.x, v.y);
            xs[t * XPAD + 2 * r + 1] = make_float2(v.z, v.w);
        }
    }
    __syncthreads();

    const int j   = tid & 63;
    const int wid = tid >> 6;

    // xj for all t: 40 VGPRs, loaded once per block (2-way bank alias = free)
    float2 xj[TT];
#pragma unroll
    for (int t = 0; t < TT; ++t) xj[t] = xs[t * XPAD + j];

#pragma unroll 1
    for (int c = 0; c < 8; ++c) {
        const int i0 = half * 32 + c * 4;
        const int i  = i0 + wid;
        const float kill = (i == j) ? 0.0f : 1.0f;

        float cst[TT];
#pragma unroll
        for (int t = 0; t < TT; ++t) {
            float2 xi = xs[t * XPAD + i];      // wave-uniform -> broadcast
            float dx = xi.x - xj[t].x;
            float dy = xi.y - xj[t].y;
            float d  = __builtin_amdgcn_sqrtf(dx * dx + dy * dy);
            float v  = THR - d;
            v = v > 0.0f ? v : 0.0f;
            cst[t] = v * kill;                 // diagonal -> 0
        }

        // swizzled transpose write: 5x ds_write_b128, conflict-free
#pragma unroll
        for (int kt = 0; kt < 5; ++kt) {
            int m  = 5 * tid + kt;
            int pm = (m & ~7) | ((5 * m) & 7);
            buf[pm] = make_float4(cst[4 * kt + 0], cst[4 * kt + 1],
                                  cst[4 * kt + 2], cst[4 * kt + 3]);
        }
        __syncthreads();

        // coalesced read-back + lane-contiguous global stores
        float4* op = (float4*)out + ((size_t)g * 20480 + (size_t)i0 * 320);
#pragma unroll
        for (int k = 0; k < 5; ++k) {
            int m  = k * 256 + tid;
            int pm = (m & ~7) | ((5 * m) & 7);
            op[m] = buf[pm];
        }
        __syncthreads();   // buf reused next chunk
    }
}

extern "C" void kernel_launch(void* const* d_in, const int* in_sizes, int n_in,
                              void* d_out, int out_size, void* d_ws, size_t ws_size,
                              hipStream_t stream) {
    const float* traj = (const float*)d_in[0];  // (T, B, 2) f32
    float* out = (float*)d_out;                 // G*P*P*T f32
    traj_critic_kernel<<<2 * GG, 256, 0, stream>>>(traj, out);
}

// Round 4
// 352.059 us; speedup vs baseline: 1.8998x; 1.0061x over previous
//
#include <hip/hip_runtime.h>

// Problem constants (match reference)
#define TT 20      // timesteps
#define GG 1024    // groups
#define PP 64      // pedestrians per group
#define THR 0.25f
#define XPAD 65    // padded t-row stride in float2 units (64 + 1)

// LDS-only barrier: s_waitcnt lgkmcnt(0) + s_barrier, WITHOUT the vmcnt(0)
// drain hipcc emits for __syncthreads(). Our inter-thread hazards are all
// LDS (ds_write->ds_read on buf, ds_read->overwrite on buf); global stores
// have no cross-thread hazard and may stay in flight across the barrier,
// keeping the HBM write stream continuous.
#define BARRIER_LDS() asm volatile("s_waitcnt lgkmcnt(0)\n\ts_barrier" ::: "memory")

// grid = 2*GG blocks, 256 threads; block handles half a group (32 i-rows)
// in 8 chunks of 4 rows.
// Compute: thread = pair (i = i0 + tid>>6, j = tid&63); xj[t] in 40 VGPRs,
//   xi[t] wave-uniform LDS broadcast; ~8 VALU/elem, raw v_sqrt_f32.
// Store: in-LDS transpose, block-swizzle pi(m) = (m&~7)|((5m)&7) so both
//   the stride-5 writer and stride-1 reader b128s are bank-conflict-free;
//   reader issues lane-contiguous float4 stores (1 KB per wave-store).
__global__ __launch_bounds__(256) void traj_critic_kernel(
    const float* __restrict__ traj, float* __restrict__ out)
{
    __shared__ float2 xs[TT * XPAD];   // 10400 B: xs[t*65 + p]
    __shared__ float4 buf[1280];       // 20480 B transpose buffer

    const int blk  = blockIdx.x;
    const int g    = blk >> 1;
    const int half = blk & 1;
    const int tid  = threadIdx.x;

    // ---- cooperative group load: 640 float4 -> padded LDS ----
    {
        const float4* tg = (const float4*)traj;
        for (int u4 = tid; u4 < (TT * PP * 2 / 4); u4 += 256) {
            int t = u4 >> 5;        // 32 float4 per timestep row
            int r = u4 & 31;
            float4 v = tg[t * 32768 + g * 32 + r];
            xs[t * XPAD + 2 * r]     = make_float2(v.x, v.y);
            xs[t * XPAD + 2 * r + 1] = make_float2(v.z, v.w);
        }
    }
    BARRIER_LDS();

    const int j   = tid & 63;
    const int wid = tid >> 6;

    // xj for all t: 40 VGPRs, loaded once per block (2-way bank alias = free)
    float2 xj[TT];
#pragma unroll
    for (int t = 0; t < TT; ++t) xj[t] = xs[t * XPAD + j];

#pragma unroll 1
    for (int c = 0; c < 8; ++c) {
        const int i0 = half * 32 + c * 4;
        const int i  = i0 + wid;
        const float kill = (i == j) ? 0.0f : 1.0f;

        float cst[TT];
#pragma unroll
        for (int t = 0; t < TT; ++t) {
            float2 xi = xs[t * XPAD + i];      // wave-uniform -> broadcast
            float dx = xi.x - xj[t].x;
            float dy = xi.y - xj[t].y;
            float d  = __builtin_amdgcn_sqrtf(dx * dx + dy * dy);
            float v  = THR - d;
            v = v > 0.0f ? v : 0.0f;
            cst[t] = v * kill;                 // diagonal -> 0
        }

        // swizzled transpose write: 5x ds_write_b128, conflict-free
#pragma unroll
        for (int kt = 0; kt < 5; ++kt) {
            int m  = 5 * tid + kt;
            int pm = (m & ~7) | ((5 * m) & 7);
            buf[pm] = make_float4(cst[4 * kt + 0], cst[4 * kt + 1],
                                  cst[4 * kt + 2], cst[4 * kt + 3]);
        }
        BARRIER_LDS();   // writes visible to readers (LDS only, no vmcnt drain)

        // coalesced read-back + lane-contiguous global stores
        float4* op = (float4*)out + ((size_t)g * 20480 + (size_t)i0 * 320);
#pragma unroll
        for (int k = 0; k < 5; ++k) {
            int m  = k * 256 + tid;
            int pm = (m & ~7) | ((5 * m) & 7);
            op[m] = buf[pm];
        }
        if (c != 7) BARRIER_LDS();   // buf reused next chunk; skip on last
    }
}

extern "C" void kernel_launch(void* const* d_in, const int* in_sizes, int n_in,
                              void* d_out, int out_size, void* d_ws, size_t ws_size,
                              hipStream_t stream) {
    const float* traj = (const float*)d_in[0];  // (T, B, 2) f32
    float* out = (float*)d_out;                 // G*P*P*T f32
    traj_critic_kernel<<<2 * GG, 256, 0, stream>>>(traj, out);
}